// Round 1
// baseline (669.340 us; speedup 1.0000x reference)
//
#include <hip/hip_runtime.h>

// VanillaRNN fused kernel for MI355X (gfx950).
// B=256, T=512, D=128, H=256, O=128, all fp32 in/out.
//
// Strategy: one workgroup per batch row (256 WGs x 256 threads, 1 WG/CU).
// Thread i owns hidden unit i. W_hh row i and W_hx row i live packed-f16 in
// VGPRs for the whole kernel (constant across the 512 serial steps).
// x-projection computed fused in 32-step chunks into LDS; recurrence reads
// only the 512B h vector from LDS per step (broadcast b128 reads).
// f16 storage, fp32 accumulation via v_dot2_f32_f16, fp32 tanhf.

typedef _Float16 f16;
typedef _Float16 f16x2 __attribute__((ext_vector_type(2)));
typedef _Float16 f16x8 __attribute__((ext_vector_type(8)));
typedef float f32x4 __attribute__((ext_vector_type(4)));

#if __has_builtin(__builtin_amdgcn_fdot2)
__device__ __forceinline__ float fdot2(f16x2 a, f16x2 b, float c) {
  return __builtin_amdgcn_fdot2(a, b, c, false);
}
#else
__device__ __forceinline__ float fdot2(f16x2 a, f16x2 b, float c) {
  return c + (float)a[0] * (float)b[0] + (float)a[1] * (float)b[1];
}
#endif

#define NB 256
#define NT 512
#define ND 128
#define NH 256
#define NO 128
#define TC 32   // timesteps per chunk

__global__ __launch_bounds__(256, 1)
void rnn_fused(const float* __restrict__ x,
               const float* __restrict__ whx, const float* __restrict__ bhx,
               const float* __restrict__ whh, const float* __restrict__ bhh,
               const float* __restrict__ wph, const float* __restrict__ bph,
               float* __restrict__ out)
{
  const int b = blockIdx.x;
  const int i = threadIdx.x;   // hidden unit index 0..255

  __shared__ alignas(16) f16x2 xs2[TC][ND / 2];   // 8 KB   x chunk (f16)
  __shared__ float xwl[TC][NH];                   // 32 KB  xW chunk (f32)
  __shared__ alignas(16) f16 hbuf[2][NH];         // 1 KB   h double buffer
  __shared__ float occupancy_guard[10240];        // 40 KB: total LDS > 80KB -> 1 WG/CU

  // ---- prologue: per-thread weight rows into packed-f16 registers ----
  f16x2 whh2[NH / 2];   // 128 VGPRs
  f16x2 whx2[ND / 2];   // 64 VGPRs
  {
    const float* wr = whh + (size_t)i * NH;
    #pragma unroll
    for (int q = 0; q < NH / 4; ++q) {
      f32x4 w = *(const f32x4*)(wr + q * 4);
      f16x2 lo = {(f16)w.x, (f16)w.y};
      f16x2 hi = {(f16)w.z, (f16)w.w};
      whh2[q * 2 + 0] = lo;
      whh2[q * 2 + 1] = hi;
    }
  }
  {
    const float* wr = whx + (size_t)i * ND;
    #pragma unroll
    for (int q = 0; q < ND / 4; ++q) {
      f32x4 w = *(const f32x4*)(wr + q * 4);
      f16x2 lo = {(f16)w.x, (f16)w.y};
      f16x2 hi = {(f16)w.z, (f16)w.w};
      whx2[q * 2 + 0] = lo;
      whx2[q * 2 + 1] = hi;
    }
  }
  const float bi = bhx[i] + bhh[i];
  if (b == 0x7fffffff) occupancy_guard[i] = bi;   // never true; keeps LDS alive

  hbuf[0][i] = (f16)0.f;   // h0 = 0 (first read is after two barriers below)

  int cur = 0;
  for (int c = 0; c < NT / TC; ++c) {
    // ---- stage x[b, c*TC .. c*TC+TC, :] -> LDS as f16 (coalesced f32x4) ----
    const float* xb = x + ((size_t)b * NT + (size_t)c * TC) * ND;
    #pragma unroll
    for (int it = 0; it < 4; ++it) {
      int idx = (it * 256 + i) * 4;        // flat float index in the 4096-float chunk
      f32x4 v = *(const f32x4*)(xb + idx);
      int tc = idx >> 7;                   // / ND
      int k2 = (idx & (ND - 1)) >> 1;      // half2 index
      f16x2 lo = {(f16)v.x, (f16)v.y};
      f16x2 hi = {(f16)v.z, (f16)v.w};
      xs2[tc][k2 + 0] = lo;
      xs2[tc][k2 + 1] = hi;
    }
    __syncthreads();

    // ---- xw[tc][i] = dot(x[tc,:], W_hx[i,:]) for the whole chunk ----
    float xwacc[TC];
    #pragma unroll
    for (int tc = 0; tc < TC; ++tc) xwacc[tc] = 0.f;
    #pragma unroll
    for (int g = 0; g < ND / 8; ++g) {
      f16x2 w0 = whx2[g * 4 + 0], w1 = whx2[g * 4 + 1];
      f16x2 w2 = whx2[g * 4 + 2], w3 = whx2[g * 4 + 3];
      #pragma unroll
      for (int tc = 0; tc < TC; ++tc) {
        f16x8 xv = *(const f16x8*)&xs2[tc][g * 4];   // broadcast b128 read
        f16x2 p0 = {xv[0], xv[1]}, p1 = {xv[2], xv[3]};
        f16x2 p2 = {xv[4], xv[5]}, p3 = {xv[6], xv[7]};
        xwacc[tc] = fdot2(w3, p3, fdot2(w2, p2, fdot2(w1, p1, fdot2(w0, p0, xwacc[tc]))));
      }
    }
    #pragma unroll
    for (int tc = 0; tc < TC; ++tc) xwl[tc][i] = xwacc[tc];
    __syncthreads();

    // ---- 32 serial recurrence steps ----
    for (int s = 0; s < TC; ++s) {
      const f16x8* hr = (const f16x8*)hbuf[cur];
      float a0 = 0.f, a1 = 0.f, a2 = 0.f, a3 = 0.f;
      #pragma unroll
      for (int g = 0; g < NH / 8; ++g) {
        f16x8 hv = hr[g];                            // broadcast b128 read
        f16x2 p0 = {hv[0], hv[1]}, p1 = {hv[2], hv[3]};
        f16x2 p2 = {hv[4], hv[5]}, p3 = {hv[6], hv[7]};
        a0 = fdot2(whh2[g * 4 + 0], p0, a0);
        a1 = fdot2(whh2[g * 4 + 1], p1, a1);
        a2 = fdot2(whh2[g * 4 + 2], p2, a2);
        a3 = fdot2(whh2[g * 4 + 3], p3, a3);
      }
      float z = xwl[s][i] + bi + ((a0 + a1) + (a2 + a3));
      float hn = tanhf(z);
      float hp = __shfl_xor(hn, 1);                  // partner value for paired f16x2 store
      int nxt = cur ^ 1;
      if (!(i & 1)) {
        f16x2 pr = {(f16)hn, (f16)hp};
        ((f16x2*)hbuf[nxt])[i >> 1] = pr;            // conflict-free: lanes hit distinct banks
      }
      cur = nxt;
      __syncthreads();
    }
  }

  // ---- output projection: out[b,o] = h_T . W_ph[o,:] + b_ph[o] ----
  if (i < NO) {
    const f16* hf = hbuf[cur];
    float acc = bph[i];
    const float* wr = wph + (size_t)i * NH;
    #pragma unroll
    for (int k = 0; k < NH; k += 4) {
      f32x4 w = *(const f32x4*)(wr + k);
      acc += (float)hf[k + 0] * w.x + (float)hf[k + 1] * w.y
           + (float)hf[k + 2] * w.z + (float)hf[k + 3] * w.w;
    }
    out[(size_t)b * NO + i] = acc;
  }
}

extern "C" void kernel_launch(void* const* d_in, const int* in_sizes, int n_in,
                              void* d_out, int out_size, void* d_ws, size_t ws_size,
                              hipStream_t stream) {
  const float* x   = (const float*)d_in[0];
  const float* whx = (const float*)d_in[1];
  const float* bhx = (const float*)d_in[2];
  const float* whh = (const float*)d_in[3];
  const float* bhh = (const float*)d_in[4];
  const float* wph = (const float*)d_in[5];
  const float* bph = (const float*)d_in[6];
  float* out = (float*)d_out;

  rnn_fused<<<dim3(NB), dim3(256), 0, stream>>>(x, whx, bhx, whh, bhh, wph, bph, out);
}